// Round 15
// baseline (411.055 us; speedup 1.0000x reference)
//
#include <hip/hip_runtime.h>
#include <stdint.h>
#include <math.h>

// Problem constants
#define NN 8192     // graph nodes == GEMM K
#define HD 256      // hidden dim == GEMM N
#define BATCH 2048
#define KSPLIT 8
#define KCH (NN / KSPLIT)   // 1024 K (floats) per kblk -> 2 stages of 512

typedef __attribute__((ext_vector_type(8))) short bf16x8;
typedef __attribute__((ext_vector_type(4))) float f32x4;

static __device__ __forceinline__ uint32_t pack_bf2(float x, float y) {
  union { float f; uint32_t u; } a, b; a.f = x; b.f = y;
  uint32_t ua = a.u + 0x7FFFu + ((a.u >> 16) & 1u);
  uint32_t ub = b.u + 0x7FFFu + ((b.u >> 16) & 1u);
  return (ua >> 16) | (ub & 0xFFFF0000u);
}
static __device__ __forceinline__ float bf_lo(uint32_t u) {
  return __uint_as_float(u << 16);
}
static __device__ __forceinline__ float bf_hi(uint32_t u) {
  return __uint_as_float(u & 0xFFFF0000u);
}

// ---------------------------------------------------------------- prep:
// blocks 0..255:   emb -> Bm frag-major bf16
// blocks 256..351: conv weights -> Wm frag-major bf16
// blocks 352..367: dedup pass 1 — rep[i] = first j with same gathered A-row
extern "C" __global__ void k_prep(const float* __restrict__ emb,
                                  const float* __restrict__ k1,
                                  const float* __restrict__ k2,
                                  const int* __restrict__ bx,
                                  const int* __restrict__ by,
                                  uint16_t* __restrict__ Bm,
                                  uint16_t* __restrict__ Wm,
                                  int* __restrict__ repA,
                                  int* __restrict__ foA) {
  const int tid = threadIdx.x;
  if (blockIdx.x < 256) {
    __shared__ float ts[32][257];
    const int kc = blockIdx.x;
#pragma unroll
    for (int i = 0; i < 32; i++)
      ts[i][tid] = emb[(size_t)(kc * 32 + i) * HD + tid];
    __syncthreads();
#pragma unroll
    for (int c = 0; c < 4; c++) {
      int e = c * 256 + tid;
      int ci = e >> 6, l = e & 63;
      int g = l >> 4, col = ci * 16 + (l & 15);
      uint4 v;
      v.x = pack_bf2(ts[g * 8 + 0][col], ts[g * 8 + 1][col]);
      v.y = pack_bf2(ts[g * 8 + 2][col], ts[g * 8 + 3][col]);
      v.z = pack_bf2(ts[g * 8 + 4][col], ts[g * 8 + 5][col]);
      v.w = pack_bf2(ts[g * 8 + 6][col], ts[g * 8 + 7][col]);
      ((uint4*)Bm)[(size_t)kc * 1024 + e] = v;
    }
  } else if (blockIdx.x < 352) {
    const int c = (blockIdx.x - 256) * 256 + tid;   // 0..24575
    const int lcl = c & 63;
    const int ci = (c >> 6) % 24;
    const int kc = c / (24 * 64);
    const int j = ci * 16 + (lcl & 15);
    const int k0 = kc * 32 + ((lcl >> 4) << 3);
    float f[8];
#pragma unroll
    for (int jj = 0; jj < 8; jj++) {
      int k = k0 + jj;
      f[jj] = (j < 128) ? k1[j * 514 + 1 + k]
            : (j < 256) ? k2[(j - 128) * 1028 + 515 + k]
                        : k2[(j - 256) * 1028 + 1 + k];
    }
    uint4 v;
    v.x = pack_bf2(f[0], f[1]); v.y = pack_bf2(f[2], f[3]);
    v.z = pack_bf2(f[4], f[5]); v.w = pack_bf2(f[6], f[7]);
    *(uint4*)(Wm + (size_t)c * 8) = v;
  } else {
    __shared__ int rows[4096];
    for (int k = tid; k < 4096; k += 256)
      rows[k] = (k < BATCH) ? bx[k] : by[k - BATCH];
    __syncthreads();
    const int i = (blockIdx.x - 352) * 256 + tid;   // 0..4095
    const int my = rows[i];
    int rep = i;
    for (int j = 0; j < i; ++j)
      if (rows[j] == my) { rep = j; break; }
    repA[i] = rep;
    foA[i] = (rep == i) ? 1 : 0;
  }
}

// ---------------------------------------------------------------- scan:
// 1 block: exclusive prefix-sum of first-occurrence flags -> slot[]; emits
// uidx[i] (slot of representative), ulist[slot] (unique arows, 0-padded), nu.
extern "C" __global__ void k_scan(const int* __restrict__ foA,
                                  const int* __restrict__ repA,
                                  const int* __restrict__ bx,
                                  const int* __restrict__ by,
                                  int* __restrict__ uidx,
                                  int* __restrict__ ulist,
                                  int* __restrict__ nuOut) {
  __shared__ int slot[4096];
  __shared__ int csum[256];
  __shared__ int nuS;
  const int tid = threadIdx.x;
  const int base = tid * 16;
  int f[16];
#pragma unroll
  for (int k = 0; k < 16; ++k) f[k] = foA[base + k];
  int s = 0;
#pragma unroll
  for (int k = 0; k < 16; ++k) { slot[base + k] = s; s += f[k]; }
  csum[tid] = s;
  __syncthreads();
  if (tid == 0) {
    int acc = 0;
    for (int t = 0; t < 256; ++t) { int v = csum[t]; csum[t] = acc; acc += v; }
    nuS = acc;
    *nuOut = acc;
  }
  __syncthreads();
  const int off = csum[tid];
#pragma unroll
  for (int k = 0; k < 16; ++k) slot[base + k] += off;
  __syncthreads();
#pragma unroll
  for (int k = 0; k < 16; ++k) {
    const int i = base + k;
    const int rep = repA[i];
    const int si = slot[rep];
    uidx[i] = si;
    if (rep == i)
      ulist[si] = (i < BATCH) ? bx[i] : by[i - BATCH];
  }
  const int nu = nuS;
  for (int i = tid; i < 4096; i += 256)
    if (i >= nu) ulist[i] = 0;           // pad (computed, never read by tail)
}

// ---------------------------------------------------------------- GEMM:
// BM=64, KSPLIT=8 -> grid 512, 2 blocks/CU. Two 512-k stages, burst-staged
// (2KB/row). Stage-1 loads register-held, issued during stage-0 compute.
// DEDUP: rows come from ulist (unique A rows only); ~20% of blocks exit.
extern "C" __global__ __launch_bounds__(256, 2)
void k_gemm(const float* __restrict__ A, const uint16_t* __restrict__ Bm,
            const int* __restrict__ ulist, const int* __restrict__ nuP,
            uint16_t* __restrict__ Rp) {
  const int kblk = blockIdx.x & 7;                   // XCD = bid%8 == kblk
  const int mblk = blockIdx.x >> 3;
  if (mblk * 64 >= *nuP) return;                     // dedup early-exit
  __shared__ __align__(16) uint16_t Asm[64 * 512];   // 64KB; reused as Ct
  const int tid = threadIdx.x;
  const int wv = tid >> 6, l = tid & 63, g = l >> 4, l15 = l & 15;

  // staging geometry: row r = tid>>2, sub b = tid&3
  const int r = tid >> 2, b = tid & 3;
  const int arow = ulist[mblk * 64 + r];
  const float* aSrc = A + (size_t)arow * NN + (size_t)kblk * KCH + b * 4;
  const int ris = r >> 4, l15s = r & 15;
  const int joff = (b & 1) << 2;
  const int gb = b >> 1;

#define PACK1(v_, m_) { \
    const int kcp = (m_) >> 1; \
    const int gg = (((m_) & 1) << 1) + gb; \
    const int off = ((kcp * 4 + ris) * 64 + gg * 16 + l15s) * 8 + joff; \
    uint2 u_; u_.x = pack_bf2((v_).x, (v_).y); u_.y = pack_bf2((v_).z, (v_).w); \
    *(uint2*)(Asm + off) = u_; }

  // ---- stage 0: burst load + pack (k 0..511) ----
#pragma unroll
  for (int half = 0; half < 2; ++half) {
    float4 t[16];
#pragma unroll
    for (int m16 = 0; m16 < 16; ++m16)
      t[m16] = *(const float4*)(aSrc + (half * 16 + m16) * 16);
#pragma unroll
    for (int m16 = 0; m16 < 16; ++m16) PACK1(t[m16], half * 16 + m16);
  }
  __syncthreads();                                  // barrier 1

  f32x4 acc[4][4] = {};
  const uint16_t* bWave = Bm + (((size_t)(kblk * 32) * 16 + wv * 4) * 64 + l) * 8;

#define COMPUTE_RANGE(stage, kc0, kc1) \
  _Pragma("unroll") \
  for (int kc = (kc0); kc < (kc1); ++kc) { \
    bf16x8 bfr[4]; \
    _Pragma("unroll") \
    for (int cj = 0; cj < 4; ++cj) \
      bfr[cj] = *(const bf16x8*)(bWave + (((stage) * 16 + kc) * 16 + cj) * 512); \
    _Pragma("unroll") \
    for (int ri = 0; ri < 4; ++ri) { \
      bf16x8 af = *(const bf16x8*)(Asm + (size_t)((kc * 4 + ri) * 64 + l) * 8); \
      _Pragma("unroll") \
      for (int cj = 0; cj < 4; ++cj) \
        acc[ri][cj] = __builtin_amdgcn_mfma_f32_16x16x32_bf16( \
            af, bfr[cj], acc[ri][cj], 0, 0, 0); } }

  // ---- stage-1 prefetch (regs) overlapped with stage-0 compute ----
  float4 s2a[16];
#pragma unroll
  for (int m = 0; m < 16; ++m)
    s2a[m] = *(const float4*)(aSrc + 512 + m * 16);
  COMPUTE_RANGE(0, 0, 8)
  float4 s2b[16];
#pragma unroll
  for (int m = 0; m < 16; ++m)
    s2b[m] = *(const float4*)(aSrc + 512 + (16 + m) * 16);
  COMPUTE_RANGE(0, 8, 16)
  __syncthreads();                                  // barrier 2: LDS reads done
  // ---- pack stage 1 (k 512..1023) ----
#pragma unroll
  for (int m = 0; m < 16; ++m) PACK1(s2a[m], m)
#pragma unroll
  for (int m = 0; m < 16; ++m) PACK1(s2b[m], 16 + m)
  __syncthreads();                                  // barrier 3
  COMPUTE_RANGE(1, 0, 16)
  __syncthreads();                                  // barrier 4: Asm -> Ct

  // ---- epilogue: pack col-pairs, LDS exchange, coalesced stores ----
  uint16_t* Ct = Asm;                               // 64 x 256 bf16 = 32KB
#pragma unroll
  for (int ri = 0; ri < 4; ri++)
#pragma unroll
    for (int cj = 0; cj < 4; cj++)
#pragma unroll
      for (int rr = 0; rr < 4; rr++) {
        float v = acc[ri][cj][rr];
        float vn = __shfl_xor(v, 1);
        if ((l15 & 1) == 0) {
          int row16 = ri * 16 + g * 4 + rr;
          int col = wv * 64 + cj * 16 + l15;
          *(uint32_t*)(Ct + row16 * 256 + col) = pack_bf2(v, vn);
        }
      }
  __syncthreads();                                  // barrier 5
  {
    const int row2 = tid >> 2, cb = (tid & 3) * 64;
    const uint4* src = (const uint4*)(Ct + row2 * 256 + cb);
    uint16_t* dst = Rp + ((size_t)kblk * 4096 + mblk * 64 + row2) * HD + cb;
    uint4 v0 = src[0], v1 = src[1], v2 = src[2], v3 = src[3];
    ((uint4*)dst)[0] = v0; ((uint4*)dst)[1] = v1;
    ((uint4*)dst)[2] = v2; ((uint4*)dst)[3] = v3;
  }
#undef PACK1
#undef COMPUTE_RANGE
}

// ---------------------------------------------------------------- tail:
// 256 blocks x 8 batch rows; Rp rows fetched via uidx slot indirection.
extern "C" __global__ __launch_bounds__(256, 2)
void k_tail(const uint16_t* __restrict__ Rp, const uint16_t* __restrict__ Wm,
            const int* __restrict__ uidx,
            const float* __restrict__ b1, const float* __restrict__ b2,
            const float* __restrict__ dw, const float* __restrict__ dbias,
            float* __restrict__ out) {
  __shared__ __align__(16) uint16_t t_frag[16 * 64 * 8];   // 16 KB
  __shared__ float Cl[8][388];
  __shared__ float coef[6][128];
  const int tid = threadIdx.x;
  const int b0 = blockIdx.x * 8;
  const int wv = tid >> 6, l = tid & 63, g = l >> 4, l15 = l & 15;
  if (tid < 128) {
    coef[0][tid] = dw[tid] + dw[256 + tid];
    coef[1][tid] = dw[128 + tid] + dw[384 + tid];
    coef[2][tid] = dw[512 + tid] + dw[768 + tid];
    coef[3][tid] = dw[640 + tid] + dw[896 + tid];
    coef[4][tid] = b1[tid];
    coef[5][tid] = b2[tid];
  }
  {
    const int r = tid >> 5, c8 = (tid & 31) * 8;
    const int uq = uidx[b0 + r];
    const int ua = uidx[BATCH + b0 + r];
    float rq[8] = {}, ra[8] = {};
#pragma unroll
    for (int p = 0; p < KSPLIT; p++) {
      uint4 q4 = *(const uint4*)(Rp + ((size_t)p * 4096 + uq) * HD + c8);
      uint4 a4 = *(const uint4*)(Rp + ((size_t)p * 4096 + ua) * HD + c8);
      const uint32_t* qw = (const uint32_t*)&q4;
      const uint32_t* aw = (const uint32_t*)&a4;
#pragma unroll
      for (int w = 0; w < 4; w++) {
        rq[2 * w] += bf_lo(qw[w]); rq[2 * w + 1] += bf_hi(qw[w]);
        ra[2 * w] += bf_lo(aw[w]); ra[2 * w + 1] += bf_hi(aw[w]);
      }
    }
    uint32_t tq[4], ml[4];
#pragma unroll
    for (int w = 0; w < 4; w++) {
      float d0 = rq[2 * w] - ra[2 * w], d1 = rq[2 * w + 1] - ra[2 * w + 1];
      tq[w] = pack_bf2(d0 * d0, d1 * d1);
      ml[w] = pack_bf2(rq[2 * w] * ra[2 * w], rq[2 * w + 1] * ra[2 * w + 1]);
    }
    const int kc1 = c8 >> 5, gm = (c8 >> 3) & 3;
    const int kc2 = 8 + kc1;
    *(uint4*)(t_frag + (kc1 * 64 + gm * 16 + r) * 8) = *(uint4*)tq;
    *(uint4*)(t_frag + (kc2 * 64 + gm * 16 + r) * 8) = *(uint4*)ml;
    uint4 z = {0, 0, 0, 0};
    *(uint4*)(t_frag + (kc1 * 64 + gm * 16 + 8 + r) * 8) = z;
    *(uint4*)(t_frag + (kc2 * 64 + gm * 16 + 8 + r) * 8) = z;
  }
  __syncthreads();
  {
    f32x4 acc[6] = {};
    const uint16_t* wB = Wm + ((size_t)(wv * 6) * 64 + l) * 8;
#pragma unroll 2
    for (int kc = 0; kc < 16; kc++) {
      bf16x8 af = *(const bf16x8*)(t_frag + (kc * 64 + l) * 8);
#pragma unroll
      for (int ci = 0; ci < 6; ci++) {
        bf16x8 w = *(const bf16x8*)(wB + (size_t)kc * 12288 + ci * 512);
        acc[ci] = __builtin_amdgcn_mfma_f32_16x16x32_bf16(af, w, acc[ci], 0, 0, 0);
      }
    }
#pragma unroll
    for (int ci = 0; ci < 6; ci++)
#pragma unroll
      for (int rr = 0; rr < 4; rr++) {
        int row16 = g * 4 + rr;
        if (row16 < 8) Cl[row16][wv * 96 + ci * 16 + l15] = acc[ci][rr];
      }
  }
  __syncthreads();
  {
    const int r = tid >> 5, ch0 = (tid & 31) * 4;
    float s0 = 0.f, s1 = 0.f;
#pragma unroll
    for (int cc = 0; cc < 4; cc++) {
      const int c = ch0 + cc;
      float d1 = Cl[r][c], d2a = Cl[r][128 + c], d2b = Cl[r][256 + c];
      float bb1 = coef[4][c], bb2 = coef[5][c];
      float e1 = fmaxf(0.f, fmaxf(bb1, d1 + bb1));          // max-pool conv1
      float e2 = fmaxf(0.f, fmaxf(d2a + bb2, d2b + bb2));   // max-pool conv2
      s0 += e1 * coef[0][c] + e2 * coef[1][c];
      s1 += e1 * coef[2][c] + e2 * coef[3][c];
    }
#pragma unroll
    for (int off = 16; off >= 1; off >>= 1) {
      s0 += __shfl_xor(s0, off, 32);
      s1 += __shfl_xor(s1, off, 32);
    }
    if ((tid & 31) == 0) {
      s0 += dbias[0]; s1 += dbias[1];
      float m = fmaxf(s0, s1);
      float lse = m + logf(expf(s0 - m) + expf(s1 - m));
      out[(b0 + r) * 2] = s0 - lse;
      out[(b0 + r) * 2 + 1] = s1 - lse;
    }
  }
}

// ---------------------------------------------------------------- launch
extern "C" void kernel_launch(void* const* d_in, const int* in_sizes, int n_in,
                              void* d_out, int out_size, void* d_ws, size_t ws_size,
                              hipStream_t stream) {
  const float* emb = (const float*)d_in[0];
  const float* A   = (const float*)d_in[1];
  const float* k1  = (const float*)d_in[2];
  const float* b1  = (const float*)d_in[3];
  const float* k2  = (const float*)d_in[4];
  const float* b2  = (const float*)d_in[5];
  const float* dw  = (const float*)d_in[6];
  const float* dbi = (const float*)d_in[7];
  const int* bx = (const int*)d_in[8];
  const int* by = (const int*)d_in[9];
  float* out = (float*)d_out;
  char* ws = (char*)d_ws;
  // ws: [0,4M) Bm ; [4M,4.75M) Wm ; [8M,24M) Rp bf16 ;
  //     [24M..) dedup: foA, repA, uidx, ulist, nu (16KB each, spaced 64KB)
  uint16_t* Bm = (uint16_t*)ws;
  uint16_t* Wm = (uint16_t*)(ws + (4u << 20));
  uint16_t* Rp = (uint16_t*)(ws + (8u << 20));
  int* foA   = (int*)(ws + (24u << 20));
  int* repA  = (int*)(ws + (24u << 20) + (64u << 10));
  int* uidx  = (int*)(ws + (24u << 20) + (128u << 10));
  int* ulist = (int*)(ws + (24u << 20) + (192u << 10));
  int* nuP   = (int*)(ws + (24u << 20) + (256u << 10));

  k_prep<<<368, 256, 0, stream>>>(emb, k1, k2, bx, by, Bm, Wm, repA, foA);
  k_scan<<<1, 256, 0, stream>>>(foA, repA, bx, by, uidx, ulist, nuP);
  k_gemm<<<64 * KSPLIT, 256, 0, stream>>>(A, Bm, ulist, nuP, Rp);
  k_tail<<<BATCH / 8, 256, 0, stream>>>(Rp, Wm, uidx, b1, b2, dw, dbi, out);
}

// Round 16
// 62.783 us; speedup vs baseline: 6.5473x; 6.5473x over previous
//
#include <hip/hip_runtime.h>
#include <stdint.h>
#include <math.h>

// Problem constants
#define NN 8192     // graph nodes == GEMM K
#define HD 256      // hidden dim == GEMM N
#define BATCH 2048
#define KSPLIT 8
#define KCH (NN / KSPLIT)   // 1024 K (floats) per kblk -> 2 stages of 512

typedef __attribute__((ext_vector_type(8))) short bf16x8;
typedef __attribute__((ext_vector_type(4))) float f32x4;

static __device__ __forceinline__ uint32_t pack_bf2(float x, float y) {
  union { float f; uint32_t u; } a, b; a.f = x; b.f = y;
  uint32_t ua = a.u + 0x7FFFu + ((a.u >> 16) & 1u);
  uint32_t ub = b.u + 0x7FFFu + ((b.u >> 16) & 1u);
  return (ua >> 16) | (ub & 0xFFFF0000u);
}
static __device__ __forceinline__ float bf_lo(uint32_t u) {
  return __uint_as_float(u << 16);
}
static __device__ __forceinline__ float bf_hi(uint32_t u) {
  return __uint_as_float(u & 0xFFFF0000u);
}

// ---------------------------------------------------------------- prep:
// blocks 0..255:   emb -> Bm frag-major bf16
// blocks 256..351: conv weights -> Wm frag-major bf16
extern "C" __global__ void k_prep(const float* __restrict__ emb,
                                  const float* __restrict__ k1,
                                  const float* __restrict__ k2,
                                  uint16_t* __restrict__ Bm,
                                  uint16_t* __restrict__ Wm) {
  const int tid = threadIdx.x;
  if (blockIdx.x < 256) {
    __shared__ float ts[32][257];
    const int kc = blockIdx.x;
#pragma unroll
    for (int i = 0; i < 32; i++)
      ts[i][tid] = emb[(size_t)(kc * 32 + i) * HD + tid];
    __syncthreads();
#pragma unroll
    for (int c = 0; c < 4; c++) {
      int e = c * 256 + tid;
      int ci = e >> 6, l = e & 63;
      int g = l >> 4, col = ci * 16 + (l & 15);
      uint4 v;
      v.x = pack_bf2(ts[g * 8 + 0][col], ts[g * 8 + 1][col]);
      v.y = pack_bf2(ts[g * 8 + 2][col], ts[g * 8 + 3][col]);
      v.z = pack_bf2(ts[g * 8 + 4][col], ts[g * 8 + 5][col]);
      v.w = pack_bf2(ts[g * 8 + 6][col], ts[g * 8 + 7][col]);
      ((uint4*)Bm)[(size_t)kc * 1024 + e] = v;
    }
  } else {
    const int c = (blockIdx.x - 256) * 256 + tid;   // 0..24575
    const int lcl = c & 63;
    const int ci = (c >> 6) % 24;
    const int kc = c / (24 * 64);
    const int j = ci * 16 + (lcl & 15);
    const int k0 = kc * 32 + ((lcl >> 4) << 3);
    float f[8];
#pragma unroll
    for (int jj = 0; jj < 8; jj++) {
      int k = k0 + jj;
      f[jj] = (j < 128) ? k1[j * 514 + 1 + k]
            : (j < 256) ? k2[(j - 128) * 1028 + 515 + k]
                        : k2[(j - 256) * 1028 + 1 + k];
    }
    uint4 v;
    v.x = pack_bf2(f[0], f[1]); v.y = pack_bf2(f[2], f[3]);
    v.z = pack_bf2(f[4], f[5]); v.w = pack_bf2(f[6], f[7]);
    *(uint4*)(Wm + (size_t)c * 8) = v;
  }
}

// ---------------------------------------------------------------- dedup:
// 1 block x 1024 threads, O(N) via LDS atomicMin table (r15's O(N^2) scan
// cost 347us; this is ~20K LDS ops). Emits uidx[i] (slot of i's
// representative), ulist[slot] (unique arows, 0-padded), nu.
extern "C" __global__ __launch_bounds__(1024)
void k_dedup(const int* __restrict__ bx, const int* __restrict__ by,
             int* __restrict__ uidx, int* __restrict__ ulist,
             int* __restrict__ nuOut) {
  __shared__ int table[NN];      // arow -> first-occurrence index, then slot
  __shared__ int rows[4096];
  __shared__ int wsum[32];
  const int tid = threadIdx.x;
#pragma unroll
  for (int k = 0; k < 8; ++k) table[tid + k * 1024] = 0x7fffffff;
#pragma unroll
  for (int k = 0; k < 4; ++k) {
    const int i = tid + k * 1024;
    rows[i] = (i < BATCH) ? bx[i] : by[i - BATCH];
  }
  __syncthreads();
#pragma unroll
  for (int k = 0; k < 4; ++k) {
    const int i = tid + k * 1024;
    atomicMin(&table[rows[i]], i);
  }
  __syncthreads();
  // flags for 4 consecutive elems per thread
  const int base = tid * 4;
  int f[4], s = 0;
#pragma unroll
  for (int k = 0; k < 4; ++k) {
    const int i = base + k;
    f[k] = (table[rows[i]] == i) ? 1 : 0;
    s += f[k];
  }
  // 64-lane inclusive scan of s
  const int lane = tid & 63, wid = tid >> 6;
  int incl = s;
#pragma unroll
  for (int off = 1; off < 64; off <<= 1) {
    int v = __shfl_up(incl, off);
    if (lane >= off) incl += v;
  }
  const int excl = incl - s;
  if (lane == 63) wsum[wid] = incl;
  __syncthreads();
  if (tid == 0) {
    int acc = 0;
    for (int w = 0; w < 16; ++w) { int v = wsum[w]; wsum[w] = acc; acc += v; }
    wsum[16] = acc;
    *nuOut = acc;
  }
  __syncthreads();
  int sl = wsum[wid] + excl;
  int myslot[4];
#pragma unroll
  for (int k = 0; k < 4; ++k) { myslot[k] = sl; sl += f[k]; }
  __syncthreads();               // all flag reads of table done
#pragma unroll
  for (int k = 0; k < 4; ++k) {
    const int i = base + k;
    if (f[k]) {
      table[rows[i]] = myslot[k];        // overwrite index with slot
      ulist[myslot[k]] = rows[i];
    }
  }
  __syncthreads();
#pragma unroll
  for (int k = 0; k < 4; ++k) {
    const int i = base + k;
    uidx[i] = table[rows[i]];
  }
  const int nu = wsum[16];
  for (int i = tid; i < 4096; i += 1024)
    if (i >= nu) ulist[i] = 0;           // pad (staged by gemm, never read)
}

// ---------------------------------------------------------------- GEMM:
// BM=64, KSPLIT=8 -> grid 512, 2 blocks/CU. Two 512-k stages, burst-staged
// (2KB/row). Stage-1 loads register-held, issued during stage-0 compute.
// DEDUP: rows come from ulist (unique A rows only); ~20% of blocks exit.
extern "C" __global__ __launch_bounds__(256, 2)
void k_gemm(const float* __restrict__ A, const uint16_t* __restrict__ Bm,
            const int* __restrict__ ulist, const int* __restrict__ nuP,
            uint16_t* __restrict__ Rp) {
  const int kblk = blockIdx.x & 7;                   // XCD = bid%8 == kblk
  const int mblk = blockIdx.x >> 3;
  if (mblk * 64 >= *nuP) return;                     // dedup early-exit
  __shared__ __align__(16) uint16_t Asm[64 * 512];   // 64KB; reused as Ct
  const int tid = threadIdx.x;
  const int wv = tid >> 6, l = tid & 63, g = l >> 4, l15 = l & 15;

  // staging geometry: row r = tid>>2, sub b = tid&3
  const int r = tid >> 2, b = tid & 3;
  const int arow = ulist[mblk * 64 + r];
  const float* aSrc = A + (size_t)arow * NN + (size_t)kblk * KCH + b * 4;
  const int ris = r >> 4, l15s = r & 15;
  const int joff = (b & 1) << 2;
  const int gb = b >> 1;

#define PACK1(v_, m_) { \
    const int kcp = (m_) >> 1; \
    const int gg = (((m_) & 1) << 1) + gb; \
    const int off = ((kcp * 4 + ris) * 64 + gg * 16 + l15s) * 8 + joff; \
    uint2 u_; u_.x = pack_bf2((v_).x, (v_).y); u_.y = pack_bf2((v_).z, (v_).w); \
    *(uint2*)(Asm + off) = u_; }

  // ---- stage 0: burst load + pack (k 0..511) ----
#pragma unroll
  for (int half = 0; half < 2; ++half) {
    float4 t[16];
#pragma unroll
    for (int m16 = 0; m16 < 16; ++m16)
      t[m16] = *(const float4*)(aSrc + (half * 16 + m16) * 16);
#pragma unroll
    for (int m16 = 0; m16 < 16; ++m16) PACK1(t[m16], half * 16 + m16);
  }
  __syncthreads();                                  // barrier 1

  f32x4 acc[4][4] = {};
  const uint16_t* bWave = Bm + (((size_t)(kblk * 32) * 16 + wv * 4) * 64 + l) * 8;

#define COMPUTE_RANGE(stage, kc0, kc1) \
  _Pragma("unroll") \
  for (int kc = (kc0); kc < (kc1); ++kc) { \
    bf16x8 bfr[4]; \
    _Pragma("unroll") \
    for (int cj = 0; cj < 4; ++cj) \
      bfr[cj] = *(const bf16x8*)(bWave + (((stage) * 16 + kc) * 16 + cj) * 512); \
    _Pragma("unroll") \
    for (int ri = 0; ri < 4; ++ri) { \
      bf16x8 af = *(const bf16x8*)(Asm + (size_t)((kc * 4 + ri) * 64 + l) * 8); \
      _Pragma("unroll") \
      for (int cj = 0; cj < 4; ++cj) \
        acc[ri][cj] = __builtin_amdgcn_mfma_f32_16x16x32_bf16( \
            af, bfr[cj], acc[ri][cj], 0, 0, 0); } }

  // ---- stage-1 prefetch (regs) overlapped with stage-0 compute ----
  float4 s2a[16];
#pragma unroll
  for (int m = 0; m < 16; ++m)
    s2a[m] = *(const float4*)(aSrc + 512 + m * 16);
  COMPUTE_RANGE(0, 0, 8)
  float4 s2b[16];
#pragma unroll
  for (int m = 0; m < 16; ++m)
    s2b[m] = *(const float4*)(aSrc + 512 + (16 + m) * 16);
  COMPUTE_RANGE(0, 8, 16)
  __syncthreads();                                  // barrier 2: LDS reads done
  // ---- pack stage 1 (k 512..1023) ----
#pragma unroll
  for (int m = 0; m < 16; ++m) PACK1(s2a[m], m)
#pragma unroll
  for (int m = 0; m < 16; ++m) PACK1(s2b[m], 16 + m)
  __syncthreads();                                  // barrier 3
  COMPUTE_RANGE(1, 0, 16)
  __syncthreads();                                  // barrier 4: Asm -> Ct

  // ---- epilogue: pack col-pairs, LDS exchange, coalesced stores ----
  uint16_t* Ct = Asm;                               // 64 x 256 bf16 = 32KB
#pragma unroll
  for (int ri = 0; ri < 4; ri++)
#pragma unroll
    for (int cj = 0; cj < 4; cj++)
#pragma unroll
      for (int rr = 0; rr < 4; rr++) {
        float v = acc[ri][cj][rr];
        float vn = __shfl_xor(v, 1);
        if ((l15 & 1) == 0) {
          int row16 = ri * 16 + g * 4 + rr;
          int col = wv * 64 + cj * 16 + l15;
          *(uint32_t*)(Ct + row16 * 256 + col) = pack_bf2(v, vn);
        }
      }
  __syncthreads();                                  // barrier 5
  {
    const int row2 = tid >> 2, cb = (tid & 3) * 64;
    const uint4* src = (const uint4*)(Ct + row2 * 256 + cb);
    uint16_t* dst = Rp + ((size_t)kblk * 4096 + mblk * 64 + row2) * HD + cb;
    uint4 v0 = src[0], v1 = src[1], v2 = src[2], v3 = src[3];
    ((uint4*)dst)[0] = v0; ((uint4*)dst)[1] = v1;
    ((uint4*)dst)[2] = v2; ((uint4*)dst)[3] = v3;
  }
#undef PACK1
#undef COMPUTE_RANGE
}

// ---------------------------------------------------------------- tail:
// 256 blocks x 8 batch rows; Rp rows fetched via uidx slot indirection.
extern "C" __global__ __launch_bounds__(256, 2)
void k_tail(const uint16_t* __restrict__ Rp, const uint16_t* __restrict__ Wm,
            const int* __restrict__ uidx,
            const float* __restrict__ b1, const float* __restrict__ b2,
            const float* __restrict__ dw, const float* __restrict__ dbias,
            float* __restrict__ out) {
  __shared__ __align__(16) uint16_t t_frag[16 * 64 * 8];   // 16 KB
  __shared__ float Cl[8][388];
  __shared__ float coef[6][128];
  const int tid = threadIdx.x;
  const int b0 = blockIdx.x * 8;
  const int wv = tid >> 6, l = tid & 63, g = l >> 4, l15 = l & 15;
  if (tid < 128) {
    coef[0][tid] = dw[tid] + dw[256 + tid];
    coef[1][tid] = dw[128 + tid] + dw[384 + tid];
    coef[2][tid] = dw[512 + tid] + dw[768 + tid];
    coef[3][tid] = dw[640 + tid] + dw[896 + tid];
    coef[4][tid] = b1[tid];
    coef[5][tid] = b2[tid];
  }
  {
    const int r = tid >> 5, c8 = (tid & 31) * 8;
    const int uq = uidx[b0 + r];
    const int ua = uidx[BATCH + b0 + r];
    float rq[8] = {}, ra[8] = {};
#pragma unroll
    for (int p = 0; p < KSPLIT; p++) {
      uint4 q4 = *(const uint4*)(Rp + ((size_t)p * 4096 + uq) * HD + c8);
      uint4 a4 = *(const uint4*)(Rp + ((size_t)p * 4096 + ua) * HD + c8);
      const uint32_t* qw = (const uint32_t*)&q4;
      const uint32_t* aw = (const uint32_t*)&a4;
#pragma unroll
      for (int w = 0; w < 4; w++) {
        rq[2 * w] += bf_lo(qw[w]); rq[2 * w + 1] += bf_hi(qw[w]);
        ra[2 * w] += bf_lo(aw[w]); ra[2 * w + 1] += bf_hi(aw[w]);
      }
    }
    uint32_t tq[4], ml[4];
#pragma unroll
    for (int w = 0; w < 4; w++) {
      float d0 = rq[2 * w] - ra[2 * w], d1 = rq[2 * w + 1] - ra[2 * w + 1];
      tq[w] = pack_bf2(d0 * d0, d1 * d1);
      ml[w] = pack_bf2(rq[2 * w] * ra[2 * w], rq[2 * w + 1] * ra[2 * w + 1]);
    }
    const int kc1 = c8 >> 5, gm = (c8 >> 3) & 3;
    const int kc2 = 8 + kc1;
    *(uint4*)(t_frag + (kc1 * 64 + gm * 16 + r) * 8) = *(uint4*)tq;
    *(uint4*)(t_frag + (kc2 * 64 + gm * 16 + r) * 8) = *(uint4*)ml;
    uint4 z = {0, 0, 0, 0};
    *(uint4*)(t_frag + (kc1 * 64 + gm * 16 + 8 + r) * 8) = z;
    *(uint4*)(t_frag + (kc2 * 64 + gm * 16 + 8 + r) * 8) = z;
  }
  __syncthreads();
  {
    f32x4 acc[6] = {};
    const uint16_t* wB = Wm + ((size_t)(wv * 6) * 64 + l) * 8;
#pragma unroll 2
    for (int kc = 0; kc < 16; kc++) {
      bf16x8 af = *(const bf16x8*)(t_frag + (kc * 64 + l) * 8);
#pragma unroll
      for (int ci = 0; ci < 6; ci++) {
        bf16x8 w = *(const bf16x8*)(wB + (size_t)kc * 12288 + ci * 512);
        acc[ci] = __builtin_amdgcn_mfma_f32_16x16x32_bf16(af, w, acc[ci], 0, 0, 0);
      }
    }
#pragma unroll
    for (int ci = 0; ci < 6; ci++)
#pragma unroll
      for (int rr = 0; rr < 4; rr++) {
        int row16 = g * 4 + rr;
        if (row16 < 8) Cl[row16][wv * 96 + ci * 16 + l15] = acc[ci][rr];
      }
  }
  __syncthreads();
  {
    const int r = tid >> 5, ch0 = (tid & 31) * 4;
    float s0 = 0.f, s1 = 0.f;
#pragma unroll
    for (int cc = 0; cc < 4; cc++) {
      const int c = ch0 + cc;
      float d1 = Cl[r][c], d2a = Cl[r][128 + c], d2b = Cl[r][256 + c];
      float bb1 = coef[4][c], bb2 = coef[5][c];
      float e1 = fmaxf(0.f, fmaxf(bb1, d1 + bb1));          // max-pool conv1
      float e2 = fmaxf(0.f, fmaxf(d2a + bb2, d2b + bb2));   // max-pool conv2
      s0 += e1 * coef[0][c] + e2 * coef[1][c];
      s1 += e1 * coef[2][c] + e2 * coef[3][c];
    }
#pragma unroll
    for (int off = 16; off >= 1; off >>= 1) {
      s0 += __shfl_xor(s0, off, 32);
      s1 += __shfl_xor(s1, off, 32);
    }
    if ((tid & 31) == 0) {
      s0 += dbias[0]; s1 += dbias[1];
      float m = fmaxf(s0, s1);
      float lse = m + logf(expf(s0 - m) + expf(s1 - m));
      out[(b0 + r) * 2] = s0 - lse;
      out[(b0 + r) * 2 + 1] = s1 - lse;
    }
  }
}

// ---------------------------------------------------------------- launch
extern "C" void kernel_launch(void* const* d_in, const int* in_sizes, int n_in,
                              void* d_out, int out_size, void* d_ws, size_t ws_size,
                              hipStream_t stream) {
  const float* emb = (const float*)d_in[0];
  const float* A   = (const float*)d_in[1];
  const float* k1  = (const float*)d_in[2];
  const float* b1  = (const float*)d_in[3];
  const float* k2  = (const float*)d_in[4];
  const float* b2  = (const float*)d_in[5];
  const float* dw  = (const float*)d_in[6];
  const float* dbi = (const float*)d_in[7];
  const int* bx = (const int*)d_in[8];
  const int* by = (const int*)d_in[9];
  float* out = (float*)d_out;
  char* ws = (char*)d_ws;
  // ws: [0,4M) Bm ; [4M,4.75M) Wm ; [8M,24M) Rp bf16 ;
  //     [24M..) dedup: uidx, ulist, nu (spaced 64KB)
  uint16_t* Bm = (uint16_t*)ws;
  uint16_t* Wm = (uint16_t*)(ws + (4u << 20));
  uint16_t* Rp = (uint16_t*)(ws + (8u << 20));
  int* uidx  = (int*)(ws + (24u << 20));
  int* ulist = (int*)(ws + (24u << 20) + (64u << 10));
  int* nuP   = (int*)(ws + (24u << 20) + (128u << 10));

  k_dedup<<<1, 1024, 0, stream>>>(bx, by, uidx, ulist, nuP);
  k_prep<<<352, 256, 0, stream>>>(emb, k1, k2, Bm, Wm);
  k_gemm<<<64 * KSPLIT, 256, 0, stream>>>(A, Bm, ulist, nuP, Rp);
  k_tail<<<BATCH / 8, 256, 0, stream>>>(Rp, Wm, uidx, b1, b2, dw, dbi, out);
}

// Round 17
// 61.678 us; speedup vs baseline: 6.6645x; 1.0179x over previous
//
#include <hip/hip_runtime.h>
#include <stdint.h>
#include <math.h>

// Problem constants
#define NN 8192     // graph nodes == GEMM K
#define HD 256      // hidden dim == GEMM N
#define BATCH 2048
#define KSPLIT 8
#define KCH (NN / KSPLIT)   // 1024 K (floats) per kblk -> 2 stages of 512

typedef __attribute__((ext_vector_type(8))) short bf16x8;
typedef __attribute__((ext_vector_type(4))) float f32x4;

static __device__ __forceinline__ uint32_t pack_bf2(float x, float y) {
  union { float f; uint32_t u; } a, b; a.f = x; b.f = y;
  uint32_t ua = a.u + 0x7FFFu + ((a.u >> 16) & 1u);
  uint32_t ub = b.u + 0x7FFFu + ((b.u >> 16) & 1u);
  return (ua >> 16) | (ub & 0xFFFF0000u);
}
static __device__ __forceinline__ float bf_lo(uint32_t u) {
  return __uint_as_float(u << 16);
}
static __device__ __forceinline__ float bf_hi(uint32_t u) {
  return __uint_as_float(u & 0xFFFF0000u);
}

// ---------------------------------------------------------------- prep:
// blocks 0..255:   emb -> Bm frag-major bf16
// blocks 256..351: conv weights -> Wm frag-major bf16
// block  352:      dedup (O(N) LDS atomicMin table) -> uidx/ulist/nu
//                  (folded in so it runs CONCURRENTLY with prep blocks;
//                   r16's separate 1-block launch serialized ~8us)
extern "C" __global__ void k_prep(const float* __restrict__ emb,
                                  const float* __restrict__ k1,
                                  const float* __restrict__ k2,
                                  const int* __restrict__ bx,
                                  const int* __restrict__ by,
                                  uint16_t* __restrict__ Bm,
                                  uint16_t* __restrict__ Wm,
                                  int* __restrict__ uidx,
                                  int* __restrict__ ulist,
                                  int* __restrict__ nuOut) {
  __shared__ __align__(16) char smem[49664];
  const int tid = threadIdx.x;
  if (blockIdx.x < 256) {
    float (*ts)[257] = (float(*)[257])smem;      // 32.9 KB
    const int kc = blockIdx.x;
#pragma unroll
    for (int i = 0; i < 32; i++)
      ts[i][tid] = emb[(size_t)(kc * 32 + i) * HD + tid];
    __syncthreads();
#pragma unroll
    for (int c = 0; c < 4; c++) {
      int e = c * 256 + tid;
      int ci = e >> 6, l = e & 63;
      int g = l >> 4, col = ci * 16 + (l & 15);
      uint4 v;
      v.x = pack_bf2(ts[g * 8 + 0][col], ts[g * 8 + 1][col]);
      v.y = pack_bf2(ts[g * 8 + 2][col], ts[g * 8 + 3][col]);
      v.z = pack_bf2(ts[g * 8 + 4][col], ts[g * 8 + 5][col]);
      v.w = pack_bf2(ts[g * 8 + 6][col], ts[g * 8 + 7][col]);
      ((uint4*)Bm)[(size_t)kc * 1024 + e] = v;
    }
  } else if (blockIdx.x < 352) {
    const int c = (blockIdx.x - 256) * 256 + tid;   // 0..24575
    const int lcl = c & 63;
    const int ci = (c >> 6) % 24;
    const int kc = c / (24 * 64);
    const int j = ci * 16 + (lcl & 15);
    const int k0 = kc * 32 + ((lcl >> 4) << 3);
    float f[8];
#pragma unroll
    for (int jj = 0; jj < 8; jj++) {
      int k = k0 + jj;
      f[jj] = (j < 128) ? k1[j * 514 + 1 + k]
            : (j < 256) ? k2[(j - 128) * 1028 + 515 + k]
                        : k2[(j - 256) * 1028 + 1 + k];
    }
    uint4 v;
    v.x = pack_bf2(f[0], f[1]); v.y = pack_bf2(f[2], f[3]);
    v.z = pack_bf2(f[4], f[5]); v.w = pack_bf2(f[6], f[7]);
    *(uint4*)(Wm + (size_t)c * 8) = v;
  } else {
    // ---- dedup block (256 threads, 16 elems/thread) ----
    int* table = (int*)smem;                     // 32 KB: arow -> idx, then slot
    int* rows  = (int*)(smem + 32768);           // 16 KB
    int* wsum  = (int*)(smem + 49152);           // 5 ints
#pragma unroll
    for (int k = 0; k < 32; ++k) table[tid + k * 256] = 0x7fffffff;
#pragma unroll
    for (int k = 0; k < 16; ++k) {
      const int i = tid + k * 256;
      rows[i] = (i < BATCH) ? bx[i] : by[i - BATCH];
    }
    __syncthreads();
#pragma unroll
    for (int k = 0; k < 16; ++k) {
      const int i = tid + k * 256;
      atomicMin(&table[rows[i]], i);
    }
    __syncthreads();
    const int base = tid * 16;
    int f[16], s = 0;
#pragma unroll
    for (int k = 0; k < 16; ++k) {
      const int i = base + k;
      f[k] = (table[rows[i]] == i) ? 1 : 0;
      s += f[k];
    }
    const int lane = tid & 63, wid = tid >> 6;
    int incl = s;
#pragma unroll
    for (int off = 1; off < 64; off <<= 1) {
      int v = __shfl_up(incl, off);
      if (lane >= off) incl += v;
    }
    const int excl = incl - s;
    if (lane == 63) wsum[wid] = incl;
    __syncthreads();
    if (tid == 0) {
      int acc = 0;
      for (int w = 0; w < 4; ++w) { int v = wsum[w]; wsum[w] = acc; acc += v; }
      wsum[4] = acc;
      *nuOut = acc;
    }
    __syncthreads();
    int sl = wsum[wid] + excl;
    int myslot[16];
#pragma unroll
    for (int k = 0; k < 16; ++k) { myslot[k] = sl; sl += f[k]; }
    __syncthreads();             // all flag reads of table done
#pragma unroll
    for (int k = 0; k < 16; ++k) {
      const int i = base + k;
      if (f[k]) {
        table[rows[i]] = myslot[k];      // overwrite index with slot
        ulist[myslot[k]] = rows[i];
      }
    }
    __syncthreads();
#pragma unroll
    for (int k = 0; k < 16; ++k) {
      const int i = base + k;
      uidx[i] = table[rows[i]];
    }
    const int nu = wsum[4];
    for (int i = tid; i < 4096; i += 256)
      if (i >= nu) ulist[i] = 0;         // pad (staged by gemm, never read)
  }
}

// ---------------------------------------------------------------- GEMM:
// BM=64, KSPLIT=8 -> grid 512, 2 blocks/CU. Two 512-k stages, burst-staged
// (2KB/row). Stage-1 loads register-held, issued during stage-0 compute.
// DEDUP: rows come from ulist (unique A rows only); ~20% of blocks exit.
extern "C" __global__ __launch_bounds__(256, 2)
void k_gemm(const float* __restrict__ A, const uint16_t* __restrict__ Bm,
            const int* __restrict__ ulist, const int* __restrict__ nuP,
            uint16_t* __restrict__ Rp) {
  const int kblk = blockIdx.x & 7;                   // XCD = bid%8 == kblk
  const int mblk = blockIdx.x >> 3;
  if (mblk * 64 >= *nuP) return;                     // dedup early-exit
  __shared__ __align__(16) uint16_t Asm[64 * 512];   // 64KB; reused as Ct
  const int tid = threadIdx.x;
  const int wv = tid >> 6, l = tid & 63, g = l >> 4, l15 = l & 15;

  // staging geometry: row r = tid>>2, sub b = tid&3
  const int r = tid >> 2, b = tid & 3;
  const int arow = ulist[mblk * 64 + r];
  const float* aSrc = A + (size_t)arow * NN + (size_t)kblk * KCH + b * 4;
  const int ris = r >> 4, l15s = r & 15;
  const int joff = (b & 1) << 2;
  const int gb = b >> 1;

#define PACK1(v_, m_) { \
    const int kcp = (m_) >> 1; \
    const int gg = (((m_) & 1) << 1) + gb; \
    const int off = ((kcp * 4 + ris) * 64 + gg * 16 + l15s) * 8 + joff; \
    uint2 u_; u_.x = pack_bf2((v_).x, (v_).y); u_.y = pack_bf2((v_).z, (v_).w); \
    *(uint2*)(Asm + off) = u_; }

  // ---- stage 0: burst load + pack (k 0..511) ----
#pragma unroll
  for (int half = 0; half < 2; ++half) {
    float4 t[16];
#pragma unroll
    for (int m16 = 0; m16 < 16; ++m16)
      t[m16] = *(const float4*)(aSrc + (half * 16 + m16) * 16);
#pragma unroll
    for (int m16 = 0; m16 < 16; ++m16) PACK1(t[m16], half * 16 + m16);
  }
  __syncthreads();                                  // barrier 1

  f32x4 acc[4][4] = {};
  const uint16_t* bWave = Bm + (((size_t)(kblk * 32) * 16 + wv * 4) * 64 + l) * 8;

#define COMPUTE_RANGE(stage, kc0, kc1) \
  _Pragma("unroll") \
  for (int kc = (kc0); kc < (kc1); ++kc) { \
    bf16x8 bfr[4]; \
    _Pragma("unroll") \
    for (int cj = 0; cj < 4; ++cj) \
      bfr[cj] = *(const bf16x8*)(bWave + (((stage) * 16 + kc) * 16 + cj) * 512); \
    _Pragma("unroll") \
    for (int ri = 0; ri < 4; ++ri) { \
      bf16x8 af = *(const bf16x8*)(Asm + (size_t)((kc * 4 + ri) * 64 + l) * 8); \
      _Pragma("unroll") \
      for (int cj = 0; cj < 4; ++cj) \
        acc[ri][cj] = __builtin_amdgcn_mfma_f32_16x16x32_bf16( \
            af, bfr[cj], acc[ri][cj], 0, 0, 0); } }

  // ---- stage-1 prefetch (regs) overlapped with stage-0 compute ----
  float4 s2a[16];
#pragma unroll
  for (int m = 0; m < 16; ++m)
    s2a[m] = *(const float4*)(aSrc + 512 + m * 16);
  COMPUTE_RANGE(0, 0, 8)
  float4 s2b[16];
#pragma unroll
  for (int m = 0; m < 16; ++m)
    s2b[m] = *(const float4*)(aSrc + 512 + (16 + m) * 16);
  COMPUTE_RANGE(0, 8, 16)
  __syncthreads();                                  // barrier 2: LDS reads done
  // ---- pack stage 1 (k 512..1023) ----
#pragma unroll
  for (int m = 0; m < 16; ++m) PACK1(s2a[m], m)
#pragma unroll
  for (int m = 0; m < 16; ++m) PACK1(s2b[m], 16 + m)
  __syncthreads();                                  // barrier 3
  COMPUTE_RANGE(1, 0, 16)
  __syncthreads();                                  // barrier 4: Asm -> Ct

  // ---- epilogue: pack col-pairs, LDS exchange, coalesced stores ----
  uint16_t* Ct = Asm;                               // 64 x 256 bf16 = 32KB
#pragma unroll
  for (int ri = 0; ri < 4; ri++)
#pragma unroll
    for (int cj = 0; cj < 4; cj++)
#pragma unroll
      for (int rr = 0; rr < 4; rr++) {
        float v = acc[ri][cj][rr];
        float vn = __shfl_xor(v, 1);
        if ((l15 & 1) == 0) {
          int row16 = ri * 16 + g * 4 + rr;
          int col = wv * 64 + cj * 16 + l15;
          *(uint32_t*)(Ct + row16 * 256 + col) = pack_bf2(v, vn);
        }
      }
  __syncthreads();                                  // barrier 5
  {
    const int row2 = tid >> 2, cb = (tid & 3) * 64;
    const uint4* src = (const uint4*)(Ct + row2 * 256 + cb);
    uint16_t* dst = Rp + ((size_t)kblk * 4096 + mblk * 64 + row2) * HD + cb;
    uint4 v0 = src[0], v1 = src[1], v2 = src[2], v3 = src[3];
    ((uint4*)dst)[0] = v0; ((uint4*)dst)[1] = v1;
    ((uint4*)dst)[2] = v2; ((uint4*)dst)[3] = v3;
  }
#undef PACK1
#undef COMPUTE_RANGE
}

// ---------------------------------------------------------------- tail:
// 256 blocks x 8 batch rows; Rp rows fetched via uidx slot indirection.
extern "C" __global__ __launch_bounds__(256, 2)
void k_tail(const uint16_t* __restrict__ Rp, const uint16_t* __restrict__ Wm,
            const int* __restrict__ uidx,
            const float* __restrict__ b1, const float* __restrict__ b2,
            const float* __restrict__ dw, const float* __restrict__ dbias,
            float* __restrict__ out) {
  __shared__ __align__(16) uint16_t t_frag[16 * 64 * 8];   // 16 KB
  __shared__ float Cl[8][388];
  __shared__ float coef[6][128];
  const int tid = threadIdx.x;
  const int b0 = blockIdx.x * 8;
  const int wv = tid >> 6, l = tid & 63, g = l >> 4, l15 = l & 15;
  if (tid < 128) {
    coef[0][tid] = dw[tid] + dw[256 + tid];
    coef[1][tid] = dw[128 + tid] + dw[384 + tid];
    coef[2][tid] = dw[512 + tid] + dw[768 + tid];
    coef[3][tid] = dw[640 + tid] + dw[896 + tid];
    coef[4][tid] = b1[tid];
    coef[5][tid] = b2[tid];
  }
  {
    const int r = tid >> 5, c8 = (tid & 31) * 8;
    const int uq = uidx[b0 + r];
    const int ua = uidx[BATCH + b0 + r];
    float rq[8] = {}, ra[8] = {};
#pragma unroll
    for (int p = 0; p < KSPLIT; p++) {
      uint4 q4 = *(const uint4*)(Rp + ((size_t)p * 4096 + uq) * HD + c8);
      uint4 a4 = *(const uint4*)(Rp + ((size_t)p * 4096 + ua) * HD + c8);
      const uint32_t* qw = (const uint32_t*)&q4;
      const uint32_t* aw = (const uint32_t*)&a4;
#pragma unroll
      for (int w = 0; w < 4; w++) {
        rq[2 * w] += bf_lo(qw[w]); rq[2 * w + 1] += bf_hi(qw[w]);
        ra[2 * w] += bf_lo(aw[w]); ra[2 * w + 1] += bf_hi(aw[w]);
      }
    }
    uint32_t tq[4], ml[4];
#pragma unroll
    for (int w = 0; w < 4; w++) {
      float d0 = rq[2 * w] - ra[2 * w], d1 = rq[2 * w + 1] - ra[2 * w + 1];
      tq[w] = pack_bf2(d0 * d0, d1 * d1);
      ml[w] = pack_bf2(rq[2 * w] * ra[2 * w], rq[2 * w + 1] * ra[2 * w + 1]);
    }
    const int kc1 = c8 >> 5, gm = (c8 >> 3) & 3;
    const int kc2 = 8 + kc1;
    *(uint4*)(t_frag + (kc1 * 64 + gm * 16 + r) * 8) = *(uint4*)tq;
    *(uint4*)(t_frag + (kc2 * 64 + gm * 16 + r) * 8) = *(uint4*)ml;
    uint4 z = {0, 0, 0, 0};
    *(uint4*)(t_frag + (kc1 * 64 + gm * 16 + 8 + r) * 8) = z;
    *(uint4*)(t_frag + (kc2 * 64 + gm * 16 + 8 + r) * 8) = z;
  }
  __syncthreads();
  {
    f32x4 acc[6] = {};
    const uint16_t* wB = Wm + ((size_t)(wv * 6) * 64 + l) * 8;
#pragma unroll 2
    for (int kc = 0; kc < 16; kc++) {
      bf16x8 af = *(const bf16x8*)(t_frag + (kc * 64 + l) * 8);
#pragma unroll
      for (int ci = 0; ci < 6; ci++) {
        bf16x8 w = *(const bf16x8*)(wB + (size_t)kc * 12288 + ci * 512);
        acc[ci] = __builtin_amdgcn_mfma_f32_16x16x32_bf16(af, w, acc[ci], 0, 0, 0);
      }
    }
#pragma unroll
    for (int ci = 0; ci < 6; ci++)
#pragma unroll
      for (int rr = 0; rr < 4; rr++) {
        int row16 = g * 4 + rr;
        if (row16 < 8) Cl[row16][wv * 96 + ci * 16 + l15] = acc[ci][rr];
      }
  }
  __syncthreads();
  {
    const int r = tid >> 5, ch0 = (tid & 31) * 4;
    float s0 = 0.f, s1 = 0.f;
#pragma unroll
    for (int cc = 0; cc < 4; cc++) {
      const int c = ch0 + cc;
      float d1 = Cl[r][c], d2a = Cl[r][128 + c], d2b = Cl[r][256 + c];
      float bb1 = coef[4][c], bb2 = coef[5][c];
      float e1 = fmaxf(0.f, fmaxf(bb1, d1 + bb1));          // max-pool conv1
      float e2 = fmaxf(0.f, fmaxf(d2a + bb2, d2b + bb2));   // max-pool conv2
      s0 += e1 * coef[0][c] + e2 * coef[1][c];
      s1 += e1 * coef[2][c] + e2 * coef[3][c];
    }
#pragma unroll
    for (int off = 16; off >= 1; off >>= 1) {
      s0 += __shfl_xor(s0, off, 32);
      s1 += __shfl_xor(s1, off, 32);
    }
    if ((tid & 31) == 0) {
      s0 += dbias[0]; s1 += dbias[1];
      float m = fmaxf(s0, s1);
      float lse = m + logf(expf(s0 - m) + expf(s1 - m));
      out[(b0 + r) * 2] = s0 - lse;
      out[(b0 + r) * 2 + 1] = s1 - lse;
    }
  }
}

// ---------------------------------------------------------------- launch
extern "C" void kernel_launch(void* const* d_in, const int* in_sizes, int n_in,
                              void* d_out, int out_size, void* d_ws, size_t ws_size,
                              hipStream_t stream) {
  const float* emb = (const float*)d_in[0];
  const float* A   = (const float*)d_in[1];
  const float* k1  = (const float*)d_in[2];
  const float* b1  = (const float*)d_in[3];
  const float* k2  = (const float*)d_in[4];
  const float* b2  = (const float*)d_in[5];
  const float* dw  = (const float*)d_in[6];
  const float* dbi = (const float*)d_in[7];
  const int* bx = (const int*)d_in[8];
  const int* by = (const int*)d_in[9];
  float* out = (float*)d_out;
  char* ws = (char*)d_ws;
  // ws: [0,4M) Bm ; [4M,4.75M) Wm ; [8M,24M) Rp bf16 ;
  //     [24M..) dedup: uidx, ulist, nu (spaced 64KB)
  uint16_t* Bm = (uint16_t*)ws;
  uint16_t* Wm = (uint16_t*)(ws + (4u << 20));
  uint16_t* Rp = (uint16_t*)(ws + (8u << 20));
  int* uidx  = (int*)(ws + (24u << 20));
  int* ulist = (int*)(ws + (24u << 20) + (64u << 10));
  int* nuP   = (int*)(ws + (24u << 20) + (128u << 10));

  k_prep<<<353, 256, 0, stream>>>(emb, k1, k2, bx, by, Bm, Wm, uidx, ulist, nuP);
  k_gemm<<<64 * KSPLIT, 256, 0, stream>>>(A, Bm, ulist, nuP, Rp);
  k_tail<<<BATCH / 8, 256, 0, stream>>>(Rp, Wm, uidx, b1, b2, dw, dbi, out);
}